// Round 3
// baseline (2852.134 us; speedup 1.0000x reference)
//
#include <hip/hip_runtime.h>

#define D 128

// ---------- bf16 helpers (raw ushort representation) ----------
__device__ __forceinline__ float bf2f(unsigned short u) {
    union { unsigned int i; float f; } v;
    v.i = ((unsigned int)u) << 16;
    return v.f;
}
__device__ __forceinline__ unsigned short f2bf(float f) {
    union { float f; unsigned int i; } v;
    v.f = f;
    unsigned int x = v.i;
    unsigned int round_bit = (x >> 16) & 1u;   // round-to-nearest-even
    x += 0x7fffu + round_bit;
    return (unsigned short)(x >> 16);
}

// ---------- runtime layout probes ----------
// flags[0] = 1 if index arrays are int64 (edge_type values are in [1,32], never 0:
//            if stored as int64, all int32 words at odd offsets are zero high-halves).
// flags[1] = 1 if float arrays are fp32 (bf16 N(0,1) data never has exponent-field
//            > 140; fp32 data reinterpreted as ushorts has uniform low-words, so
//            some exponent-field > 140 with P ~ 1-3e-17 over 64 samples).
__global__ void detect_kernel(const int* __restrict__ et_i32,
                              const unsigned short* __restrict__ emb_u16,
                              int* __restrict__ flags) {
    int lane = threadIdx.x;                    // 0..63
    int v = et_i32[2 * lane + 1];
    unsigned long long b_i64 = __ballot(v != 0);

    unsigned short a = emb_u16[2 * lane];
    unsigned short c = emb_u16[2 * lane + 1];
    int e1 = (a >> 7) & 0xFF;
    int e2 = (c >> 7) & 0xFF;
    unsigned long long b_f32 = __ballot(e1 > 140 || e2 > 140);

    if (lane == 0) {
        flags[0] = (b_i64 == 0ULL) ? 1 : 0;
        flags[1] = (b_f32 != 0ULL) ? 1 : 0;
    }
}

__device__ __forceinline__ int idx_at(const void* p, long long i, bool i64) {
    return i64 ? (int)((const long long*)p)[i] : ((const int*)p)[i];
}

// load 4 consecutive float-typed elements starting at row*D + lane*4
__device__ __forceinline__ float4 load4(const void* base, size_t row, int lane, bool f32) {
    if (f32) {
        return ((const float4*)((const float*)base + row * D))[lane];
    } else {
        ushort4 u = ((const ushort4*)((const unsigned short*)base + row * D))[lane];
        float4 r;
        r.x = bf2f(u.x); r.y = bf2f(u.y); r.z = bf2f(u.z); r.w = bf2f(u.w);
        return r;
    }
}

// ---------- KG edge scatter: ent_acc[head] += emb[tail] * weight[rel] ----------
// 32 threads per edge, 4 dims/thread.
__global__ void kg_edge_kernel(const void* __restrict__ emb,
                               const void* __restrict__ edge_index,
                               const void* __restrict__ edge_type,
                               const void* __restrict__ weight,
                               float* __restrict__ ent_acc,
                               float* __restrict__ counts,
                               const int* __restrict__ flags,
                               int n_edges) {
    int t = blockIdx.x * blockDim.x + threadIdx.x;
    int e = t >> 5;
    int lane = t & 31;
    if (e >= n_edges) return;

    bool i64 = flags[0] != 0;
    bool f32 = flags[1] != 0;

    int head = idx_at(edge_index, e, i64);
    int tail = idx_at(edge_index, (long long)n_edges + e, i64);
    int rel  = idx_at(edge_type, e, i64) - 1;

    float4 tv = load4(emb,    (size_t)tail, lane, f32);
    float4 wv = load4(weight, (size_t)rel,  lane, f32);

    float* dst = ent_acc + (size_t)head * D + lane * 4;
    unsafeAtomicAdd(dst + 0, tv.x * wv.x);
    unsafeAtomicAdd(dst + 1, tv.y * wv.y);
    unsafeAtomicAdd(dst + 2, tv.z * wv.z);
    unsafeAtomicAdd(dst + 3, tv.w * wv.w);

    if (lane == 0) unsafeAtomicAdd(counts + head, 1.0f);
}

// ---------- interaction scatter: usr_acc[row] += val * emb[col] ----------
__global__ void interact_kernel(const void* __restrict__ emb,
                                const void* __restrict__ rows,
                                const void* __restrict__ cols,
                                const void* __restrict__ vals,
                                float* __restrict__ usr_acc,
                                const int* __restrict__ flags,
                                int nnz) {
    int t = blockIdx.x * blockDim.x + threadIdx.x;
    int i = t >> 5;
    int lane = t & 31;
    if (i >= nnz) return;

    bool i64 = flags[0] != 0;
    bool f32 = flags[1] != 0;

    int r = idx_at(rows, i, i64);
    int c = idx_at(cols, i, i64);
    float v = f32 ? ((const float*)vals)[i] : bf2f(((const unsigned short*)vals)[i]);

    float4 ev = load4(emb, (size_t)c, lane, f32);

    float* dst = usr_acc + (size_t)r * D + lane * 4;
    unsafeAtomicAdd(dst + 0, v * ev.x);
    unsafeAtomicAdd(dst + 1, v * ev.y);
    unsafeAtomicAdd(dst + 2, v * ev.z);
    unsafeAtomicAdd(dst + 3, v * ev.w);
}

// ---------- finalize entity: mean + cast to output dtype ----------
__global__ void finalize_ent_kernel(const float* __restrict__ acc,
                                    const float* __restrict__ counts,
                                    void* __restrict__ out,
                                    const int* __restrict__ flags,
                                    int n_entities) {
    int t = blockIdx.x * blockDim.x + threadIdx.x;
    int total4 = n_entities * (D / 4);
    if (t >= total4) return;
    int row = t >> 5;                          // 32 quads per row
    float rcp = 1.0f / fmaxf(counts[row], 1.0f);
    float4 a = ((const float4*)acc)[t];
    a.x *= rcp; a.y *= rcp; a.z *= rcp; a.w *= rcp;
    if (flags[1]) {
        ((float4*)out)[t] = a;
    } else {
        ushort4 o;
        o.x = f2bf(a.x); o.y = f2bf(a.y); o.z = f2bf(a.z); o.w = f2bf(a.w);
        ((ushort4*)out)[t] = o;
    }
}

// ---------- finalize user: cast to output dtype (offset past entity rows) ----------
__global__ void finalize_usr_kernel(const float* __restrict__ acc,
                                    void* __restrict__ out,
                                    const int* __restrict__ flags,
                                    int n_entities, int n_users) {
    int t = blockIdx.x * blockDim.x + threadIdx.x;
    int total4 = n_users * (D / 4);
    if (t >= total4) return;
    int off = n_entities * (D / 4);
    float4 a = ((const float4*)acc)[t];
    if (flags[1]) {
        ((float4*)out)[off + t] = a;
    } else {
        ushort4 o;
        o.x = f2bf(a.x); o.y = f2bf(a.y); o.z = f2bf(a.z); o.w = f2bf(a.w);
        ((ushort4*)out)[off + t] = o;
    }
}

extern "C" void kernel_launch(void* const* d_in, const int* in_sizes, int n_in,
                              void* d_out, int out_size, void* d_ws, size_t ws_size,
                              hipStream_t stream) {
    const void* emb  = d_in[0];   // [n_entities][D] bf16 or fp32
    const void* ei   = d_in[1];   // [2][n_edges]    int32 or int64
    const void* et   = d_in[2];   // [n_edges]
    const void* rows = d_in[3];   // [nnz]
    const void* cols = d_in[4];   // [nnz]
    const void* vals = d_in[5];   // [nnz] bf16 or fp32

    // weight = last input with >=256 elements (32*128=4096); robust to whether
    // the python scalar n_users is materialized as d_in[6].
    const void* weight = d_in[n_in - 1];
    for (int i = n_in - 1; i >= 5; --i) {
        if (in_sizes[i] >= 256) { weight = d_in[i]; break; }
    }

    int n_entities = in_sizes[0] / D;
    int n_edges    = in_sizes[2];
    int nnz        = in_sizes[5];
    int n_users    = out_size / D - n_entities;   // avoid device read of scalar

    // Phased ws layout (peak ~51.6 MB instead of 77.2 MB):
    //   phase E: [ent_acc: n_entities*D floats][counts: n_entities floats][flags: 2 int]
    //   phase U: [usr_acc: n_users*D floats]  (reuses front; flags region untouched)
    float* ent_acc = (float*)d_ws;
    float* usr_acc = (float*)d_ws;
    float* counts  = ent_acc + (size_t)n_entities * D;
    int*   flags   = (int*)(counts + n_entities);

    const int tpb = 256;

    // ---- phase E ----
    hipMemsetAsync(d_ws, 0, ((size_t)n_entities * D + n_entities) * sizeof(float), stream);
    detect_kernel<<<1, 64, 0, stream>>>((const int*)et, (const unsigned short*)emb, flags);
    {
        long long threads = (long long)n_edges * 32;
        int blocks = (int)((threads + tpb - 1) / tpb);
        kg_edge_kernel<<<blocks, tpb, 0, stream>>>(emb, ei, et, weight,
                                                   ent_acc, counts, flags, n_edges);
    }
    {
        int total4 = n_entities * (D / 4);
        int blocks = (total4 + tpb - 1) / tpb;
        finalize_ent_kernel<<<blocks, tpb, 0, stream>>>(ent_acc, counts, d_out,
                                                        flags, n_entities);
    }

    // ---- phase U ----
    hipMemsetAsync(d_ws, 0, (size_t)n_users * D * sizeof(float), stream);
    {
        long long threads = (long long)nnz * 32;
        int blocks = (int)((threads + tpb - 1) / tpb);
        interact_kernel<<<blocks, tpb, 0, stream>>>(emb, rows, cols, vals,
                                                    usr_acc, flags, nnz);
    }
    {
        int total4 = n_users * (D / 4);
        int blocks = (total4 + tpb - 1) / tpb;
        finalize_usr_kernel<<<blocks, tpb, 0, stream>>>(usr_acc, d_out, flags,
                                                        n_entities, n_users);
    }
}

// Round 5
// 802.475 us; speedup vs baseline: 3.5542x; 3.5542x over previous
//
#include <hip/hip_runtime.h>

#define D 128

// ---------- bf16 helpers (raw ushort representation) ----------
__device__ __forceinline__ float bf2f(unsigned short u) {
    union { unsigned int i; float f; } v;
    v.i = ((unsigned int)u) << 16;
    return v.f;
}
__device__ __forceinline__ unsigned short f2bf(float f) {
    union { float f; unsigned int i; } v;
    v.f = f;
    unsigned int x = v.i;
    unsigned int round_bit = (x >> 16) & 1u;   // round-to-nearest-even
    x += 0x7fffu + round_bit;
    return (unsigned short)(x >> 16);
}

// ---------- runtime layout probes (unchanged from R3 — these made it pass) ----------
__global__ void detect_kernel(const int* __restrict__ et_i32,
                              const unsigned short* __restrict__ emb_u16,
                              int* __restrict__ flags) {
    int lane = threadIdx.x;                    // 0..63
    int v = et_i32[2 * lane + 1];
    unsigned long long b_i64 = __ballot(v != 0);

    unsigned short a = emb_u16[2 * lane];
    unsigned short c = emb_u16[2 * lane + 1];
    int e1 = (a >> 7) & 0xFF;
    int e2 = (c >> 7) & 0xFF;
    unsigned long long b_f32 = __ballot(e1 > 140 || e2 > 140);

    if (lane == 0) {
        flags[0] = (b_i64 == 0ULL) ? 1 : 0;   // 1 => indices are int64
        flags[1] = (b_f32 != 0ULL) ? 1 : 0;   // 1 => floats are fp32
    }
}

__device__ __forceinline__ int idx_at(const void* p, long long i, bool i64) {
    return i64 ? (int)((const long long*)p)[i] : ((const int*)p)[i];
}

// load 2 consecutive float-typed elements at row*D + lane*2
__device__ __forceinline__ float2 loadrow2(const void* base, int row, int lane, bool f32) {
    if (f32) {
        return ((const float2*)((const float*)base + (size_t)row * D))[lane];
    } else {
        unsigned int u = ((const unsigned int*)((const unsigned short*)base + (size_t)row * D))[lane];
        float2 r;
        r.x = bf2f((unsigned short)(u & 0xFFFFu));
        r.y = bf2f((unsigned short)(u >> 16));
        return r;
    }
}

__device__ __forceinline__ void store2(void* out, size_t o, float x, float y, bool f32) {
    if (f32) {
        float2 t; t.x = x; t.y = y;
        *(float2*)((float*)out + o) = t;
    } else {
        unsigned int u = (unsigned int)f2bf(x) | ((unsigned int)f2bf(y) << 16);
        *(unsigned int*)((unsigned short*)out + o) = u;
    }
}

// ---------- CSR build: histogram ----------
__global__ void hist_kernel(const void* __restrict__ arr, int* __restrict__ cnt,
                            const int* __restrict__ flags, int n) {
    int i = blockIdx.x * blockDim.x + threadIdx.x;
    if (i >= n) return;
    int r = idx_at(arr, i, flags[0] != 0);
    atomicAdd(&cnt[r], 1);
}

// ---------- CSR build: single-workgroup exclusive scan (n up to ~100K) ----------
// Also zeroes cnt[] in place so it can be reused as the scatter cursor.
__global__ void scan_kernel(int* __restrict__ cnt, int* __restrict__ off, int n) {
    __shared__ int sums[256];
    int tid = threadIdx.x;
    int chunk = (n + 255) / 256;
    int beg = tid * chunk;
    int end = min(beg + chunk, n);
    int s = 0;
    for (int i = beg; i < end; ++i) s += cnt[i];
    sums[tid] = s;
    __syncthreads();
    for (int ofs = 1; ofs < 256; ofs <<= 1) {
        int t = (tid >= ofs) ? sums[tid - ofs] : 0;
        __syncthreads();
        sums[tid] += t;
        __syncthreads();
    }
    int prefix = sums[tid] - s;                // exclusive prefix of this chunk
    for (int i = beg; i < end; ++i) {
        int c = cnt[i];
        off[i] = prefix;
        prefix += c;
        cnt[i] = 0;                            // reset -> reuse as cursor
    }
    if (end >= n) off[n] = prefix;             // total (dup writes carry same value)
}

// ---------- CSR build: scatter pre-decoded pairs ----------
// entity side: pairs = {tail, rel}; cur[] is the zeroed cnt[]
__global__ void scatter_e_kernel(const void* __restrict__ ei, const void* __restrict__ et,
                                 const int* __restrict__ off, int* __restrict__ cur,
                                 int2* __restrict__ pairs, const int* __restrict__ flags,
                                 int n_edges) {
    int i = blockIdx.x * blockDim.x + threadIdx.x;
    if (i >= n_edges) return;
    bool i64 = flags[0] != 0;
    int head = idx_at(ei, i, i64);
    int tail = idx_at(ei, (long long)n_edges + i, i64);
    int rel  = idx_at(et, i, i64) - 1;
    int pos = off[head] + atomicAdd(&cur[head], 1);
    int2 p; p.x = tail; p.y = rel;
    pairs[pos] = p;
}

// user side: pairs = {col, float_bits(val)}
__global__ void scatter_u_kernel(const void* __restrict__ rows, const void* __restrict__ cols,
                                 const void* __restrict__ vals,
                                 const int* __restrict__ off, int* __restrict__ cur,
                                 int2* __restrict__ pairs, const int* __restrict__ flags,
                                 int nnz) {
    int i = blockIdx.x * blockDim.x + threadIdx.x;
    if (i >= nnz) return;
    bool i64 = flags[0] != 0;
    bool f32 = flags[1] != 0;
    int r = idx_at(rows, i, i64);
    int c = idx_at(cols, i, i64);
    float v = f32 ? ((const float*)vals)[i] : bf2f(((const unsigned short*)vals)[i]);
    int pos = off[r] + atomicAdd(&cur[r], 1);
    int2 p; p.x = c; p.y = __float_as_int(v);
    pairs[pos] = p;
}

// ---------- aggregate: one wave per entity row ----------
__global__ void agg_entity_kernel(const void* __restrict__ emb, const void* __restrict__ weight,
                                  const int* __restrict__ off, const int2* __restrict__ pairs,
                                  void* __restrict__ out, const int* __restrict__ flags,
                                  int n_entities) {
    int gid = blockIdx.x * blockDim.x + threadIdx.x;
    int w = gid >> 6;
    int lane = gid & 63;
    if (w >= n_entities) return;
    bool f32 = flags[1] != 0;
    int beg = off[w], end = off[w + 1];
    float ax = 0.f, ay = 0.f;
    int j = beg;
    for (; j + 1 < end; j += 2) {              // 2-deep for latency overlap
        int2 p0 = pairs[j];
        int2 p1 = pairs[j + 1];
        float2 e0 = loadrow2(emb, p0.x, lane, f32);
        float2 w0 = loadrow2(weight, p0.y, lane, f32);
        float2 e1 = loadrow2(emb, p1.x, lane, f32);
        float2 w1 = loadrow2(weight, p1.y, lane, f32);
        ax += e0.x * w0.x + e1.x * w1.x;
        ay += e0.y * w0.y + e1.y * w1.y;
    }
    if (j < end) {
        int2 p = pairs[j];
        float2 e = loadrow2(emb, p.x, lane, f32);
        float2 wv = loadrow2(weight, p.y, lane, f32);
        ax += e.x * wv.x;
        ay += e.y * wv.y;
    }
    float rcp = 1.0f / fmaxf((float)(end - beg), 1.0f);
    size_t o = (size_t)w * D + lane * 2;
    store2(out, o, ax * rcp, ay * rcp, f32);
}

// ---------- aggregate: one wave per user row ----------
__global__ void agg_user_kernel(const void* __restrict__ emb,
                                const int* __restrict__ off, const int2* __restrict__ pairs,
                                void* __restrict__ out, const int* __restrict__ flags,
                                int n_entities, int n_users) {
    int gid = blockIdx.x * blockDim.x + threadIdx.x;
    int w = gid >> 6;
    int lane = gid & 63;
    if (w >= n_users) return;
    bool f32 = flags[1] != 0;
    int beg = off[w], end = off[w + 1];
    float ax = 0.f, ay = 0.f;
    int j = beg;
    for (; j + 1 < end; j += 2) {
        int2 p0 = pairs[j];
        int2 p1 = pairs[j + 1];
        float v0 = __int_as_float(p0.y);
        float v1 = __int_as_float(p1.y);
        float2 e0 = loadrow2(emb, p0.x, lane, f32);
        float2 e1 = loadrow2(emb, p1.x, lane, f32);
        ax += v0 * e0.x + v1 * e1.x;
        ay += v0 * e0.y + v1 * e1.y;
    }
    if (j < end) {
        int2 p = pairs[j];
        float v = __int_as_float(p.y);
        float2 e = loadrow2(emb, p.x, lane, f32);
        ax += v * e.x;
        ay += v * e.y;
    }
    size_t o = ((size_t)n_entities + w) * D + lane * 2;
    store2(out, o, ax, ay, f32);
}

extern "C" void kernel_launch(void* const* d_in, const int* in_sizes, int n_in,
                              void* d_out, int out_size, void* d_ws, size_t ws_size,
                              hipStream_t stream) {
    const void* emb  = d_in[0];   // [n_entities][D] bf16 or fp32
    const void* ei   = d_in[1];   // [2][n_edges]    int32 or int64
    const void* et   = d_in[2];   // [n_edges]
    const void* rows = d_in[3];   // [nnz]
    const void* cols = d_in[4];   // [nnz]
    const void* vals = d_in[5];   // [nnz] bf16 or fp32

    // weight = last input with >=256 elements (robust to scalar presence)
    const void* weight = d_in[n_in - 1];
    for (int i = n_in - 1; i >= 5; --i) {
        if (in_sizes[i] >= 256) { weight = d_in[i]; break; }
    }

    int n_entities = in_sizes[0] / D;
    int n_edges    = in_sizes[2];
    int nnz        = in_sizes[5];
    int n_users    = out_size / D - n_entities;

    // ws layout (cnt doubles as scatter cursor after scan zeroes it):
    //   [pairs_e: n_edges int2][pairs_u: nnz int2]
    //   [off_e: n_entities+1][off_u: n_users+1][cnt_e: n_entities][cnt_u: n_users][flags: 2]
    char* p = (char*)d_ws;
    int2* pairs_e = (int2*)p;                    p += (size_t)n_edges * sizeof(int2);
    int2* pairs_u = (int2*)p;                    p += (size_t)nnz * sizeof(int2);
    int*  off_e   = (int*)p;                     p += (size_t)(n_entities + 1) * sizeof(int);
    int*  off_u   = (int*)p;                     p += (size_t)(n_users + 1) * sizeof(int);
    int*  cnt_e   = (int*)p;                     p += (size_t)n_entities * sizeof(int);
    int*  cnt_u   = (int*)p;                     p += (size_t)n_users * sizeof(int);
    int*  flags   = (int*)p;

    size_t zero_bytes = ((size_t)n_entities + n_users + 2) * sizeof(int);
    (void)hipMemsetAsync(cnt_e, 0, zero_bytes, stream);

    const int tpb = 256;

    detect_kernel<<<1, 64, 0, stream>>>((const int*)et, (const unsigned short*)emb, flags);

    // histogram
    hist_kernel<<<(n_edges + tpb - 1) / tpb, tpb, 0, stream>>>(ei, cnt_e, flags, n_edges);
    hist_kernel<<<(nnz + tpb - 1) / tpb, tpb, 0, stream>>>(rows, cnt_u, flags, nnz);

    // exclusive scan -> row offsets (also zeroes cnt for reuse as cursor)
    scan_kernel<<<1, tpb, 0, stream>>>(cnt_e, off_e, n_entities);
    scan_kernel<<<1, tpb, 0, stream>>>(cnt_u, off_u, n_users);

    // scatter pre-decoded pairs
    scatter_e_kernel<<<(n_edges + tpb - 1) / tpb, tpb, 0, stream>>>(
        ei, et, off_e, cnt_e, pairs_e, flags, n_edges);
    scatter_u_kernel<<<(nnz + tpb - 1) / tpb, tpb, 0, stream>>>(
        rows, cols, vals, off_u, cnt_u, pairs_u, flags, nnz);

    // gather-aggregate, one wave per output row, write d_out exactly once
    {
        long long threads = (long long)n_entities * 64;
        agg_entity_kernel<<<(int)((threads + tpb - 1) / tpb), tpb, 0, stream>>>(
            emb, weight, off_e, pairs_e, d_out, flags, n_entities);
    }
    {
        long long threads = (long long)n_users * 64;
        agg_user_kernel<<<(int)((threads + tpb - 1) / tpb), tpb, 0, stream>>>(
            emb, off_u, pairs_u, d_out, flags, n_entities, n_users);
    }
}

// Round 6
// 470.991 us; speedup vs baseline: 6.0556x; 1.7038x over previous
//
#include <hip/hip_runtime.h>

#define D 128

// ---------- bf16 helpers (raw ushort representation) ----------
__device__ __forceinline__ float bf2f(unsigned short u) {
    union { unsigned int i; float f; } v;
    v.i = ((unsigned int)u) << 16;
    return v.f;
}
__device__ __forceinline__ unsigned short f2bf(float f) {
    union { float f; unsigned int i; } v;
    v.f = f;
    unsigned int x = v.i;
    unsigned int round_bit = (x >> 16) & 1u;   // round-to-nearest-even
    x += 0x7fffu + round_bit;
    return (unsigned short)(x >> 16);
}

// ---------- runtime layout probes (unchanged — these made it pass) ----------
__global__ void detect_kernel(const int* __restrict__ et_i32,
                              const unsigned short* __restrict__ emb_u16,
                              int* __restrict__ flags) {
    int lane = threadIdx.x;                    // 0..63
    int v = et_i32[2 * lane + 1];
    unsigned long long b_i64 = __ballot(v != 0);

    unsigned short a = emb_u16[2 * lane];
    unsigned short c = emb_u16[2 * lane + 1];
    int e1 = (a >> 7) & 0xFF;
    int e2 = (c >> 7) & 0xFF;
    unsigned long long b_f32 = __ballot(e1 > 140 || e2 > 140);

    if (lane == 0) {
        flags[0] = (b_i64 == 0ULL) ? 1 : 0;   // 1 => indices are int64
        flags[1] = (b_f32 != 0ULL) ? 1 : 0;   // 1 => floats are fp32
    }
}

__device__ __forceinline__ int idx_at(const void* p, long long i, bool i64) {
    return i64 ? (int)((const long long*)p)[i] : ((const int*)p)[i];
}

// load 2 consecutive float-typed elements at row*D + lane*2
__device__ __forceinline__ float2 loadrow2(const void* base, int row, int lane, bool f32) {
    if (f32) {
        return ((const float2*)((const float*)base + (size_t)row * D))[lane];
    } else {
        unsigned int u = ((const unsigned int*)((const unsigned short*)base + (size_t)row * D))[lane];
        float2 r;
        r.x = bf2f((unsigned short)(u & 0xFFFFu));
        r.y = bf2f((unsigned short)(u >> 16));
        return r;
    }
}

__device__ __forceinline__ void store2(void* out, size_t o, float x, float y, bool f32) {
    if (f32) {
        float2 t; t.x = x; t.y = y;
        *(float2*)((float*)out + o) = t;
    } else {
        unsigned int u = (unsigned int)f2bf(x) | ((unsigned int)f2bf(y) << 16);
        *(unsigned int*)((unsigned short*)out + o) = u;
    }
}

// ---------- histogram into concatenated counter array ----------
__global__ void hist_kernel(const void* __restrict__ arr, int* __restrict__ cnt,
                            const int* __restrict__ flags, int n) {
    int i = blockIdx.x * blockDim.x + threadIdx.x;
    if (i >= n) return;
    int r = idx_at(arr, i, flags[0] != 0);
    atomicAdd(&cnt[r], 1);
}

// ---------- hierarchical exclusive scan (3 phases, 256-wide tiles) ----------
__device__ __forceinline__ int block_scan_excl_256(int v, int* total) {
    __shared__ int tmp[256];
    int tid = threadIdx.x;
    tmp[tid] = v;
    __syncthreads();
    #pragma unroll
    for (int ofs = 1; ofs < 256; ofs <<= 1) {
        int t = (tid >= ofs) ? tmp[tid - ofs] : 0;
        __syncthreads();
        tmp[tid] += t;
        __syncthreads();
    }
    int incl = tmp[tid];
    *total = tmp[255];
    __syncthreads();                           // safe for reuse
    return incl - v;
}

// phase 1: per-tile sums
__global__ void scan_p1(const int* __restrict__ cnt, int* __restrict__ bsums, int n) {
    int i = blockIdx.x * 256 + threadIdx.x;
    int v = (i < n) ? cnt[i] : 0;
    int total;
    block_scan_excl_256(v, &total);
    if (threadIdx.x == 0) bsums[blockIdx.x] = total;
}

// phase 2: one block exclusive-scans the tile sums in place (nb up to ~64K)
__global__ void scan_p2(int* __restrict__ bsums, int nb) {
    int tid = threadIdx.x;
    int chunk = (nb + 255) / 256;
    int beg = tid * chunk;
    int end = min(beg + chunk, nb);
    int s = 0;
    for (int i = beg; i < end; ++i) s += bsums[i];
    int total;
    int run = block_scan_excl_256(s, &total);
    for (int i = beg; i < end; ++i) {
        int c = bsums[i];
        bsums[i] = run;
        run += c;
    }
}

// phase 3: recombine -> off[], zero cnt[] for cursor reuse
__global__ void scan_p3(int* __restrict__ cnt, const int* __restrict__ bsums,
                        int* __restrict__ off, int n) {
    int i = blockIdx.x * 256 + threadIdx.x;
    int v = (i < n) ? cnt[i] : 0;
    int total;
    int excl = block_scan_excl_256(v, &total);
    int base = bsums[blockIdx.x];
    if (i < n) {
        off[i] = base + excl;
        cnt[i] = 0;
        if (i == n - 1) off[n] = base + excl + v;
    }
}

// ---------- scatter pre-decoded pairs (combined pairs array) ----------
// entity side: pairs = {tail, rel}
__global__ void scatter_e_kernel(const void* __restrict__ ei, const void* __restrict__ et,
                                 const int* __restrict__ off, int* __restrict__ cur,
                                 int2* __restrict__ pairs, const int* __restrict__ flags,
                                 int n_edges) {
    int i = blockIdx.x * blockDim.x + threadIdx.x;
    if (i >= n_edges) return;
    bool i64 = flags[0] != 0;
    int head = idx_at(ei, i, i64);
    int tail = idx_at(ei, (long long)n_edges + i, i64);
    int rel  = idx_at(et, i, i64) - 1;
    int pos = off[head] + atomicAdd(&cur[head], 1);
    int2 p; p.x = tail; p.y = rel;
    pairs[pos] = p;
}

// user side: pairs = {col, float_bits(val)}; rows live at cnt/off[n_entities + r]
__global__ void scatter_u_kernel(const void* __restrict__ rows, const void* __restrict__ cols,
                                 const void* __restrict__ vals,
                                 const int* __restrict__ off, int* __restrict__ cur,
                                 int2* __restrict__ pairs, const int* __restrict__ flags,
                                 int nnz, int n_entities) {
    int i = blockIdx.x * blockDim.x + threadIdx.x;
    if (i >= nnz) return;
    bool i64 = flags[0] != 0;
    bool f32 = flags[1] != 0;
    int rr = n_entities + idx_at(rows, i, i64);
    int c = idx_at(cols, i, i64);
    float v = f32 ? ((const float*)vals)[i] : bf2f(((const unsigned short*)vals)[i]);
    int pos = off[rr] + atomicAdd(&cur[rr], 1);
    int2 p; p.x = c; p.y = __float_as_int(v);
    pairs[pos] = p;
}

// ---------- aggregate: one wave per entity row ----------
__global__ void agg_entity_kernel(const void* __restrict__ emb, const void* __restrict__ weight,
                                  const int* __restrict__ off, const int2* __restrict__ pairs,
                                  void* __restrict__ out, const int* __restrict__ flags,
                                  int n_entities) {
    int gid = blockIdx.x * blockDim.x + threadIdx.x;
    int w = gid >> 6;
    int lane = gid & 63;
    if (w >= n_entities) return;
    bool f32 = flags[1] != 0;
    int beg = off[w], end = off[w + 1];
    float ax = 0.f, ay = 0.f;
    int j = beg;
    for (; j + 1 < end; j += 2) {              // 2-deep for latency overlap
        int2 p0 = pairs[j];
        int2 p1 = pairs[j + 1];
        float2 e0 = loadrow2(emb, p0.x, lane, f32);
        float2 w0 = loadrow2(weight, p0.y, lane, f32);
        float2 e1 = loadrow2(emb, p1.x, lane, f32);
        float2 w1 = loadrow2(weight, p1.y, lane, f32);
        ax += e0.x * w0.x + e1.x * w1.x;
        ay += e0.y * w0.y + e1.y * w1.y;
    }
    if (j < end) {
        int2 p = pairs[j];
        float2 e = loadrow2(emb, p.x, lane, f32);
        float2 wv = loadrow2(weight, p.y, lane, f32);
        ax += e.x * wv.x;
        ay += e.y * wv.y;
    }
    float rcp = 1.0f / fmaxf((float)(end - beg), 1.0f);
    size_t o = (size_t)w * D + lane * 2;
    store2(out, o, ax * rcp, ay * rcp, f32);
}

// ---------- aggregate: one wave per user row ----------
__global__ void agg_user_kernel(const void* __restrict__ emb,
                                const int* __restrict__ off, const int2* __restrict__ pairs,
                                void* __restrict__ out, const int* __restrict__ flags,
                                int n_entities, int n_users) {
    int gid = blockIdx.x * blockDim.x + threadIdx.x;
    int w = gid >> 6;
    int lane = gid & 63;
    if (w >= n_users) return;
    bool f32 = flags[1] != 0;
    int beg = off[n_entities + w], end = off[n_entities + w + 1];
    float ax = 0.f, ay = 0.f;
    int j = beg;
    for (; j + 1 < end; j += 2) {
        int2 p0 = pairs[j];
        int2 p1 = pairs[j + 1];
        float v0 = __int_as_float(p0.y);
        float v1 = __int_as_float(p1.y);
        float2 e0 = loadrow2(emb, p0.x, lane, f32);
        float2 e1 = loadrow2(emb, p1.x, lane, f32);
        ax += v0 * e0.x + v1 * e1.x;
        ay += v0 * e0.y + v1 * e1.y;
    }
    if (j < end) {
        int2 p = pairs[j];
        float v = __int_as_float(p.y);
        float2 e = loadrow2(emb, p.x, lane, f32);
        ax += v * e.x;
        ay += v * e.y;
    }
    size_t o = ((size_t)n_entities + w) * D + lane * 2;
    store2(out, o, ax, ay, f32);
}

extern "C" void kernel_launch(void* const* d_in, const int* in_sizes, int n_in,
                              void* d_out, int out_size, void* d_ws, size_t ws_size,
                              hipStream_t stream) {
    const void* emb  = d_in[0];   // [n_entities][D] bf16 or fp32
    const void* ei   = d_in[1];   // [2][n_edges]    int32 or int64
    const void* et   = d_in[2];   // [n_edges]
    const void* rows = d_in[3];   // [nnz]
    const void* cols = d_in[4];   // [nnz]
    const void* vals = d_in[5];   // [nnz] bf16 or fp32

    // weight = last input with >=256 elements (robust to scalar presence)
    const void* weight = d_in[n_in - 1];
    for (int i = n_in - 1; i >= 5; --i) {
        if (in_sizes[i] >= 256) { weight = d_in[i]; break; }
    }

    int n_entities = in_sizes[0] / D;
    int n_edges    = in_sizes[2];
    int nnz        = in_sizes[5];
    int n_users    = out_size / D - n_entities;

    int n_concat = n_entities + n_users;       // concatenated row space
    int nb = (n_concat + 255) / 256;           // scan tiles

    // ws layout:
    //   [pairs: (n_edges+nnz) int2][off: n_concat+1][cnt: n_concat][bsums: nb][flags: 2]
    char* p = (char*)d_ws;
    int2* pairs = (int2*)p;                      p += (size_t)(n_edges + nnz) * sizeof(int2);
    int*  off   = (int*)p;                       p += (size_t)(n_concat + 1) * sizeof(int);
    int*  cnt   = (int*)p;                       p += (size_t)n_concat * sizeof(int);
    int*  bsums = (int*)p;                       p += (size_t)nb * sizeof(int);
    int*  flags = (int*)p;

    (void)hipMemsetAsync(cnt, 0, (size_t)n_concat * sizeof(int), stream);

    const int tpb = 256;

    detect_kernel<<<1, 64, 0, stream>>>((const int*)et, (const unsigned short*)emb, flags);

    // histogram into concatenated counters
    hist_kernel<<<(n_edges + tpb - 1) / tpb, tpb, 0, stream>>>(ei, cnt, flags, n_edges);
    hist_kernel<<<(nnz + tpb - 1) / tpb, tpb, 0, stream>>>(rows, cnt + n_entities, flags, nnz);

    // hierarchical exclusive scan (also zeroes cnt for cursor reuse)
    scan_p1<<<nb, 256, 0, stream>>>(cnt, bsums, n_concat);
    scan_p2<<<1, 256, 0, stream>>>(bsums, nb);
    scan_p3<<<nb, 256, 0, stream>>>(cnt, bsums, off, n_concat);

    // scatter pre-decoded pairs into combined array
    scatter_e_kernel<<<(n_edges + tpb - 1) / tpb, tpb, 0, stream>>>(
        ei, et, off, cnt, pairs, flags, n_edges);
    scatter_u_kernel<<<(nnz + tpb - 1) / tpb, tpb, 0, stream>>>(
        rows, cols, vals, off, cnt, pairs, flags, nnz, n_entities);

    // gather-aggregate, one wave per output row, write d_out exactly once
    {
        long long threads = (long long)n_entities * 64;
        agg_entity_kernel<<<(int)((threads + tpb - 1) / tpb), tpb, 0, stream>>>(
            emb, weight, off, pairs, d_out, flags, n_entities);
    }
    {
        long long threads = (long long)n_users * 64;
        agg_user_kernel<<<(int)((threads + tpb - 1) / tpb), tpb, 0, stream>>>(
            emb, off, pairs, d_out, flags, n_entities, n_users);
    }
}

// Round 7
// 400.761 us; speedup vs baseline: 7.1168x; 1.1752x over previous
//
#include <hip/hip_runtime.h>

#define D 128

// ---------- bf16 helpers (raw ushort representation) ----------
__device__ __forceinline__ float bf2f(unsigned short u) {
    union { unsigned int i; float f; } v;
    v.i = ((unsigned int)u) << 16;
    return v.f;
}
__device__ __forceinline__ unsigned short f2bf(float f) {
    union { float f; unsigned int i; } v;
    v.f = f;
    unsigned int x = v.i;
    unsigned int round_bit = (x >> 16) & 1u;   // round-to-nearest-even
    x += 0x7fffu + round_bit;
    return (unsigned short)(x >> 16);
}

// ---------- runtime layout probes (unchanged — these made it pass) ----------
__global__ void detect_kernel(const int* __restrict__ et_i32,
                              const unsigned short* __restrict__ emb_u16,
                              int* __restrict__ flags) {
    int lane = threadIdx.x;                    // 0..63
    int v = et_i32[2 * lane + 1];
    unsigned long long b_i64 = __ballot(v != 0);

    unsigned short a = emb_u16[2 * lane];
    unsigned short c = emb_u16[2 * lane + 1];
    int e1 = (a >> 7) & 0xFF;
    int e2 = (c >> 7) & 0xFF;
    unsigned long long b_f32 = __ballot(e1 > 140 || e2 > 140);

    if (lane == 0) {
        flags[0] = (b_i64 == 0ULL) ? 1 : 0;   // 1 => indices are int64
        flags[1] = (b_f32 != 0ULL) ? 1 : 0;   // 1 => floats are fp32
    }
}

__device__ __forceinline__ int idx_at(const void* p, long long i, bool i64) {
    return i64 ? (int)((const long long*)p)[i] : ((const int*)p)[i];
}

// ---------- merged histogram (entity heads ++ user rows) ----------
__global__ void hist_all(const void* __restrict__ ei, const void* __restrict__ rows,
                         int* __restrict__ cnt, const int* __restrict__ flags,
                         int n_edges, int nnz, int n_entities) {
    long long i = (long long)blockIdx.x * blockDim.x + threadIdx.x;
    bool i64 = flags[0] != 0;
    if (i < n_edges) {
        atomicAdd(&cnt[idx_at(ei, i, i64)], 1);
    } else if (i < (long long)n_edges + nnz) {
        atomicAdd(&cnt[n_entities + idx_at(rows, i - n_edges, i64)], 1);
    }
}

// ---------- hierarchical exclusive scan (3 phases, 256-wide tiles) ----------
__device__ __forceinline__ int block_scan_excl_256(int v, int* total) {
    __shared__ int tmp[256];
    int tid = threadIdx.x;
    tmp[tid] = v;
    __syncthreads();
    #pragma unroll
    for (int ofs = 1; ofs < 256; ofs <<= 1) {
        int t = (tid >= ofs) ? tmp[tid - ofs] : 0;
        __syncthreads();
        tmp[tid] += t;
        __syncthreads();
    }
    int incl = tmp[tid];
    *total = tmp[255];
    __syncthreads();                           // safe for reuse
    return incl - v;
}

__global__ void scan_p1(const int* __restrict__ cnt, int* __restrict__ bsums, int n) {
    int i = blockIdx.x * 256 + threadIdx.x;
    int v = (i < n) ? cnt[i] : 0;
    int total;
    block_scan_excl_256(v, &total);
    if (threadIdx.x == 0) bsums[blockIdx.x] = total;
}

__global__ void scan_p2(int* __restrict__ bsums, int nb) {
    int tid = threadIdx.x;
    int chunk = (nb + 255) / 256;
    int beg = tid * chunk;
    int end = min(beg + chunk, nb);
    int s = 0;
    for (int i = beg; i < end; ++i) s += bsums[i];
    int total;
    int run = block_scan_excl_256(s, &total);
    for (int i = beg; i < end; ++i) {
        int c = bsums[i];
        bsums[i] = run;
        run += c;
    }
}

__global__ void scan_p3(int* __restrict__ cnt, const int* __restrict__ bsums,
                        int* __restrict__ off, int n) {
    int i = blockIdx.x * 256 + threadIdx.x;
    int v = (i < n) ? cnt[i] : 0;
    int total;
    int excl = block_scan_excl_256(v, &total);
    int base = bsums[blockIdx.x];
    if (i < n) {
        off[i] = base + excl;
        cnt[i] = 0;                            // reset -> reuse as scatter cursor
        if (i == n - 1) off[n] = base + excl + v;
    }
}

// ---------- merged scatter of pre-decoded pairs ----------
// entity region: pairs = {tail, rel}; user region: pairs = {col, float_bits(val)}
__global__ void scatter_all(const void* __restrict__ ei, const void* __restrict__ et,
                            const void* __restrict__ rows, const void* __restrict__ cols,
                            const void* __restrict__ vals,
                            const int* __restrict__ off, int* __restrict__ cur,
                            int2* __restrict__ pairs, const int* __restrict__ flags,
                            int n_edges, int nnz, int n_entities) {
    long long i = (long long)blockIdx.x * blockDim.x + threadIdx.x;
    bool i64 = flags[0] != 0;
    if (i < n_edges) {
        int head = idx_at(ei, i, i64);
        int tail = idx_at(ei, (long long)n_edges + i, i64);
        int rel  = idx_at(et, i, i64) - 1;
        int pos = off[head] + atomicAdd(&cur[head], 1);
        int2 p; p.x = tail; p.y = rel;
        pairs[pos] = p;
    } else if (i < (long long)n_edges + nnz) {
        long long k = i - n_edges;
        bool f32 = flags[1] != 0;
        int rr = n_entities + idx_at(rows, k, i64);
        int c = idx_at(cols, k, i64);
        float v = f32 ? ((const float*)vals)[k] : bf2f(((const unsigned short*)vals)[k]);
        int pos = off[rr] + atomicAdd(&cur[rr], 1);
        int2 p; p.x = c; p.y = __float_as_int(v);
        pairs[pos] = p;
    }
}

// ---------- unpack 8 bf16 (uint4) -> 8 floats ----------
__device__ __forceinline__ void unpack8(uint4 q, float* e) {
    e[0] = bf2f((unsigned short)(q.x & 0xFFFFu)); e[1] = bf2f((unsigned short)(q.x >> 16));
    e[2] = bf2f((unsigned short)(q.y & 0xFFFFu)); e[3] = bf2f((unsigned short)(q.y >> 16));
    e[4] = bf2f((unsigned short)(q.z & 0xFFFFu)); e[5] = bf2f((unsigned short)(q.z >> 16));
    e[6] = bf2f((unsigned short)(q.w & 0xFFFFu)); e[7] = bf2f((unsigned short)(q.w >> 16));
}

// ---------- merged aggregate: one wave per output row, 16-lane groups ----------
// Each wave handles row w. Lanes split as 4 groups x 16: group g walks pairs
// beg+g, beg+g+4, ... ; lane (within group) m loads 16B (8 elems) of the
// gathered emb row -> one dwordx4 per row per group, 4 rows in flight.
// End: shfl_xor(16|32) sums the 4 groups; lanes g==0 store the 256B row.
__global__ void agg_all(const void* __restrict__ emb, const void* __restrict__ weight,
                        const int* __restrict__ off, const int2* __restrict__ pairs,
                        void* __restrict__ out, const int* __restrict__ flags,
                        int n_entities, int n_total) {
    int gid = blockIdx.x * blockDim.x + threadIdx.x;
    int w = gid >> 6;
    int lane = gid & 63;
    if (w >= n_total) return;
    bool f32 = flags[1] != 0;
    bool isU = (w >= n_entities);
    int m = lane & 15;
    int g = lane >> 4;
    int beg = off[w], end = off[w + 1];

    float acc[8];
    #pragma unroll
    for (int i = 0; i < 8; ++i) acc[i] = 0.f;

    if (!f32) {
        const uint4* embq = (const uint4*)emb;          // row stride 16 uint4
        if (isU) {
            for (int j = beg + g; j < end; j += 4) {
                int2 p = pairs[j];
                uint4 q = embq[(size_t)p.x * 16 + m];
                float v = __int_as_float(p.y);
                float e[8]; unpack8(q, e);
                #pragma unroll
                for (int i = 0; i < 8; ++i) acc[i] += v * e[i];
            }
        } else {
            const uint4* wq = (const uint4*)weight;
            for (int j = beg + g; j < end; j += 4) {
                int2 p = pairs[j];
                uint4 q  = embq[(size_t)p.x * 16 + m];
                uint4 qw = wq[(size_t)p.y * 16 + m];
                float e[8], wv[8]; unpack8(q, e); unpack8(qw, wv);
                #pragma unroll
                for (int i = 0; i < 8; ++i) acc[i] += e[i] * wv[i];
            }
        }
    } else {
        const float* embf = (const float*)emb;
        if (isU) {
            for (int j = beg + g; j < end; j += 4) {
                int2 p = pairs[j];
                const float4* rp = (const float4*)(embf + (size_t)p.x * D);
                float4 a = rp[m * 2], b = rp[m * 2 + 1];
                float v = __int_as_float(p.y);
                acc[0] += v * a.x; acc[1] += v * a.y; acc[2] += v * a.z; acc[3] += v * a.w;
                acc[4] += v * b.x; acc[5] += v * b.y; acc[6] += v * b.z; acc[7] += v * b.w;
            }
        } else {
            const float* wf = (const float*)weight;
            for (int j = beg + g; j < end; j += 4) {
                int2 p = pairs[j];
                const float4* rp = (const float4*)(embf + (size_t)p.x * D);
                const float4* wp = (const float4*)(wf + (size_t)p.y * D);
                float4 a = rp[m * 2], b = rp[m * 2 + 1];
                float4 wa = wp[m * 2], wb = wp[m * 2 + 1];
                acc[0] += a.x * wa.x; acc[1] += a.y * wa.y; acc[2] += a.z * wa.z; acc[3] += a.w * wa.w;
                acc[4] += b.x * wb.x; acc[5] += b.y * wb.y; acc[6] += b.z * wb.z; acc[7] += b.w * wb.w;
            }
        }
    }

    // sum the 4 pair-groups
    #pragma unroll
    for (int i = 0; i < 8; ++i) {
        acc[i] += __shfl_xor(acc[i], 16, 64);
        acc[i] += __shfl_xor(acc[i], 32, 64);
    }

    if (!isU) {
        float rcp = 1.0f / fmaxf((float)(end - beg), 1.0f);
        #pragma unroll
        for (int i = 0; i < 8; ++i) acc[i] *= rcp;
    }

    if (g == 0) {                               // lanes 0..15 store the row
        if (!f32) {
            uint4 o;
            o.x = (unsigned int)f2bf(acc[0]) | ((unsigned int)f2bf(acc[1]) << 16);
            o.y = (unsigned int)f2bf(acc[2]) | ((unsigned int)f2bf(acc[3]) << 16);
            o.z = (unsigned int)f2bf(acc[4]) | ((unsigned int)f2bf(acc[5]) << 16);
            o.w = (unsigned int)f2bf(acc[6]) | ((unsigned int)f2bf(acc[7]) << 16);
            ((uint4*)out)[(size_t)w * 16 + m] = o;
        } else {
            float4* rp = (float4*)((float*)out + (size_t)w * D);
            float4 a, b;
            a.x = acc[0]; a.y = acc[1]; a.z = acc[2]; a.w = acc[3];
            b.x = acc[4]; b.y = acc[5]; b.z = acc[6]; b.w = acc[7];
            rp[m * 2] = a;
            rp[m * 2 + 1] = b;
        }
    }
}

extern "C" void kernel_launch(void* const* d_in, const int* in_sizes, int n_in,
                              void* d_out, int out_size, void* d_ws, size_t ws_size,
                              hipStream_t stream) {
    const void* emb  = d_in[0];   // [n_entities][D] bf16 or fp32
    const void* ei   = d_in[1];   // [2][n_edges]    int32 or int64
    const void* et   = d_in[2];   // [n_edges]
    const void* rows = d_in[3];   // [nnz]
    const void* cols = d_in[4];   // [nnz]
    const void* vals = d_in[5];   // [nnz] bf16 or fp32

    // weight = last input with >=256 elements (robust to scalar presence)
    const void* weight = d_in[n_in - 1];
    for (int i = n_in - 1; i >= 5; --i) {
        if (in_sizes[i] >= 256) { weight = d_in[i]; break; }
    }

    int n_entities = in_sizes[0] / D;
    int n_edges    = in_sizes[2];
    int nnz        = in_sizes[5];
    int n_users    = out_size / D - n_entities;

    int n_concat = n_entities + n_users;       // concatenated row space
    int nb = (n_concat + 255) / 256;           // scan tiles

    // ws layout:
    //   [pairs: (n_edges+nnz) int2][off: n_concat+1][cnt: n_concat][bsums: nb][flags: 2]
    char* p = (char*)d_ws;
    int2* pairs = (int2*)p;                      p += (size_t)(n_edges + nnz) * sizeof(int2);
    int*  off   = (int*)p;                       p += (size_t)(n_concat + 1) * sizeof(int);
    int*  cnt   = (int*)p;                       p += (size_t)n_concat * sizeof(int);
    int*  bsums = (int*)p;                       p += (size_t)nb * sizeof(int);
    int*  flags = (int*)p;

    (void)hipMemsetAsync(cnt, 0, (size_t)n_concat * sizeof(int), stream);

    const int tpb = 256;

    detect_kernel<<<1, 64, 0, stream>>>((const int*)et, (const unsigned short*)emb, flags);

    // merged histogram
    {
        long long n = (long long)n_edges + nnz;
        hist_all<<<(int)((n + tpb - 1) / tpb), tpb, 0, stream>>>(
            ei, rows, cnt, flags, n_edges, nnz, n_entities);
    }

    // hierarchical exclusive scan (also zeroes cnt for cursor reuse)
    scan_p1<<<nb, 256, 0, stream>>>(cnt, bsums, n_concat);
    scan_p2<<<1, 256, 0, stream>>>(bsums, nb);
    scan_p3<<<nb, 256, 0, stream>>>(cnt, bsums, off, n_concat);

    // merged scatter
    {
        long long n = (long long)n_edges + nnz;
        scatter_all<<<(int)((n + tpb - 1) / tpb), tpb, 0, stream>>>(
            ei, et, rows, cols, vals, off, cnt, pairs, flags, n_edges, nnz, n_entities);
    }

    // merged gather-aggregate: one wave per output row
    {
        long long threads = (long long)n_concat * 64;
        agg_all<<<(int)((threads + tpb - 1) / tpb), tpb, 0, stream>>>(
            emb, weight, off, pairs, d_out, flags, n_entities, n_concat);
    }
}